// Round 1
// baseline (212.695 us; speedup 1.0000x reference)
//
#include <hip/hip_runtime.h>
#include <math.h>

#define B_   128
#define T_   50
#define MI_  32
#define E_   128
#define EW_  16
#define D_   144
#define G_   432        // 3*D
#define N_   (B_*T_)    // 6400

// ---------------------------------------------------------------------------
// K1: basket embedding.  One block per (b,t) sample, 128 threads (one per E dim).
// seq[n][0:128] = mean-pool of encode_w rows for nonzero items; seq[n][128:144] =
// wchange_w[flag].
// ---------------------------------------------------------------------------
__global__ __launch_bounds__(128) void embed_kernel(
    const int* __restrict__ x,            // [N_][33]
    const float* __restrict__ encode_w,   // [100000][128]
    const float* __restrict__ wchange_w,  // [2][16]
    float* __restrict__ seq)              // [N_][144]
{
    int n = blockIdx.x;
    int tid = threadIdx.x;
    __shared__ int xi[33];
    if (tid < 33) xi[tid] = x[n * 33 + tid];
    __syncthreads();

    float acc = 0.f;
    float cnt = 0.f;
    #pragma unroll
    for (int i = 0; i < MI_; ++i) {
        int it = xi[i];
        if (it != 0) {                       // uniform branch per block
            cnt += 1.f;
            acc += encode_w[it * E_ + tid];  // coalesced 512B row
        }
    }
    seq[n * D_ + tid] = acc / fmaxf(cnt, 1.f);
    if (tid < EW_) {
        int flag = xi[32];
        seq[n * D_ + E_ + tid] = wchange_w[flag * EW_ + tid];
    }
}

// ---------------------------------------------------------------------------
// K2/K4: C[M][N] = A[M][144] * Bw[N][144]^T + bias[N].  K fixed = 144.
// 64x64 tile, k-major LDS (pad 68 words -> conflict-free b128 reads), BK=48.
// ---------------------------------------------------------------------------
#define GK   144
#define GBK  48
#define GPAD 68

__global__ __launch_bounds__(256) void gemm_bias_kernel(
    const float* __restrict__ A,
    const float* __restrict__ Bw,
    const float* __restrict__ bias,
    float* __restrict__ C,
    int M, int N)
{
    __shared__ float As[GBK * GPAD];
    __shared__ float Bs[GBK * GPAD];

    int tid = threadIdx.x;
    int row0 = blockIdx.x * 64;
    int col0 = blockIdx.y * 64;
    int tx = tid & 15;        // col group
    int ty = tid >> 4;        // row group

    float acc[4][4] = {};

    // staging map: r = tid>>2 (tile row), kq = (tid&3) + 4*i  -> coalesced 1KB/instr
    int sr = tid >> 2;
    int skq0 = tid & 3;

    for (int k0 = 0; k0 < GK; k0 += GBK) {
        __syncthreads();
        #pragma unroll
        for (int i = 0; i < 3; ++i) {
            int kq = skq0 + i * 4;          // 0..11  (48 k / 4)
            float4 a = *(const float4*)&A[(size_t)(row0 + sr) * GK + k0 + kq * 4];
            int nrow = col0 + sr;
            float4 b = make_float4(0.f, 0.f, 0.f, 0.f);
            if (nrow < N)
                b = *(const float4*)&Bw[(size_t)nrow * GK + k0 + kq * 4];
            As[(kq * 4 + 0) * GPAD + sr] = a.x;
            As[(kq * 4 + 1) * GPAD + sr] = a.y;
            As[(kq * 4 + 2) * GPAD + sr] = a.z;
            As[(kq * 4 + 3) * GPAD + sr] = a.w;
            Bs[(kq * 4 + 0) * GPAD + sr] = b.x;
            Bs[(kq * 4 + 1) * GPAD + sr] = b.y;
            Bs[(kq * 4 + 2) * GPAD + sr] = b.z;
            Bs[(kq * 4 + 3) * GPAD + sr] = b.w;
        }
        __syncthreads();

        #pragma unroll 4
        for (int k = 0; k < GBK; ++k) {
            float4 a4 = *(const float4*)&As[k * GPAD + ty * 4]; // broadcast across tx
            float4 b4 = *(const float4*)&Bs[k * GPAD + tx * 4]; // contiguous across tx
            float av[4] = {a4.x, a4.y, a4.z, a4.w};
            float bv[4] = {b4.x, b4.y, b4.z, b4.w};
            #pragma unroll
            for (int i = 0; i < 4; ++i)
                #pragma unroll
                for (int j = 0; j < 4; ++j)
                    acc[i][j] = fmaf(av[i], bv[j], acc[i][j]);
        }
    }

    int c = col0 + tx * 4;
    if (c < N) {
        float4 bb = *(const float4*)&bias[c];
        #pragma unroll
        for (int i = 0; i < 4; ++i) {
            int r = row0 + ty * 4 + i;
            float4 o;
            o.x = acc[i][0] + bb.x;
            o.y = acc[i][1] + bb.y;
            o.z = acc[i][2] + bb.z;
            o.w = acc[i][3] + bb.w;
            *(float4*)&C[(size_t)r * N + c] = o;
        }
    }
}

// ---------------------------------------------------------------------------
// K3: GRU.  One block per batch element (recurrence independent per batch).
// 448 threads: threads 0..431 each hold one w_hh row (36 float4 = 144 VGPRs,
// weights-stationary -> zero global w traffic per step).  h lives in LDS.
// Two barriers per step.  gi prefetched before dot products.
// ---------------------------------------------------------------------------
__global__ __launch_bounds__(448, 1) void gru_kernel(
    const float* __restrict__ gi,     // [N_][432]
    const float* __restrict__ w_hh,   // [432][144]
    const float* __restrict__ b_hh,   // [432]
    const float* __restrict__ h0,     // [128][144]
    float* __restrict__ hseq,         // [N_][144]
    float* __restrict__ hlast)        // [128][144]
{
    int b = blockIdx.x;
    int tid = threadIdx.x;

    __shared__ __align__(16) float h[D_];
    __shared__ float gh[G_];

    int jrow = (tid < G_) ? tid : (G_ - 1);
    float4 w[36];
    #pragma unroll
    for (int i = 0; i < 36; ++i)
        w[i] = *(const float4*)&w_hh[(size_t)jrow * D_ + i * 4];
    float gbias = b_hh[jrow];

    if (tid < D_) h[tid] = h0[b * D_ + tid];
    __syncthreads();

    for (int t = 0; t < T_; ++t) {
        int n = b * T_ + t;
        // prefetch gi for the gate phase (hides load latency behind the dots)
        float gir = 0.f, giz = 0.f, gin = 0.f;
        if (tid < D_) {
            gir = gi[(size_t)n * G_ + tid];
            giz = gi[(size_t)n * G_ + D_ + tid];
            gin = gi[(size_t)n * G_ + 2 * D_ + tid];
        }

        if (tid < G_) {
            float a0 = 0.f, a1 = 0.f, a2 = 0.f, a3 = 0.f;
            #pragma unroll
            for (int i = 0; i < 36; i += 4) {
                float4 hv0 = *(const float4*)&h[(i + 0) * 4];
                float4 hv1 = *(const float4*)&h[(i + 1) * 4];
                float4 hv2 = *(const float4*)&h[(i + 2) * 4];
                float4 hv3 = *(const float4*)&h[(i + 3) * 4];
                a0 = fmaf(w[i + 0].x, hv0.x, a0); a0 = fmaf(w[i + 0].y, hv0.y, a0);
                a0 = fmaf(w[i + 0].z, hv0.z, a0); a0 = fmaf(w[i + 0].w, hv0.w, a0);
                a1 = fmaf(w[i + 1].x, hv1.x, a1); a1 = fmaf(w[i + 1].y, hv1.y, a1);
                a1 = fmaf(w[i + 1].z, hv1.z, a1); a1 = fmaf(w[i + 1].w, hv1.w, a1);
                a2 = fmaf(w[i + 2].x, hv2.x, a2); a2 = fmaf(w[i + 2].y, hv2.y, a2);
                a2 = fmaf(w[i + 2].z, hv2.z, a2); a2 = fmaf(w[i + 2].w, hv2.w, a2);
                a3 = fmaf(w[i + 3].x, hv3.x, a3); a3 = fmaf(w[i + 3].y, hv3.y, a3);
                a3 = fmaf(w[i + 3].z, hv3.z, a3); a3 = fmaf(w[i + 3].w, hv3.w, a3);
            }
            gh[tid] = ((a0 + a1) + (a2 + a3)) + gbias;
        }
        __syncthreads();

        if (tid < D_) {
            float r = 1.f / (1.f + __expf(-(gir + gh[tid])));
            float z = 1.f / (1.f + __expf(-(giz + gh[D_ + tid])));
            float narg = gin + r * gh[2 * D_ + tid];
            narg = fminf(fmaxf(narg, -15.f), 15.f);
            float e2 = __expf(-2.f * narg);
            float nn = (1.f - e2) / (1.f + e2);
            float hn = (1.f - z) * nn + z * h[tid];
            hseq[(size_t)n * D_ + tid] = hn;
            h[tid] = hn;
        }
        __syncthreads();
    }

    if (tid < D_) hlast[b * D_ + tid] = h[tid];
}

// ---------------------------------------------------------------------------
extern "C" void kernel_launch(void* const* d_in, const int* in_sizes, int n_in,
                              void* d_out, int out_size, void* d_ws, size_t ws_size,
                              hipStream_t stream)
{
    const int*   x         = (const int*)d_in[0];
    // d_in[1] = lengths (unused by the reference computation)
    const float* hidden    = (const float*)d_in[2];
    const float* encode_w  = (const float*)d_in[3];
    const float* wchange_w = (const float*)d_in[4];
    const float* w_ih      = (const float*)d_in[5];
    const float* w_hh      = (const float*)d_in[6];
    const float* b_ih      = (const float*)d_in[7];
    const float* b_hh      = (const float*)d_in[8];
    const float* fc_w      = (const float*)d_in[9];
    const float* fc_b      = (const float*)d_in[10];

    float* out = (float*)d_out;              // [N_][128] then [128][144]
    float* ws  = (float*)d_ws;
    float* seq  = ws;                        //   921600 floats
    float* gi   = ws + 921600;               //  2764800 floats
    float* hseq = ws + 921600 + 2764800;     //   921600 floats  (18.4 MB total)

    // K1: embedding
    embed_kernel<<<N_, 128, 0, stream>>>(x, encode_w, wchange_w, seq);

    // K2: gi = seq @ w_ih^T + b_ih   (M=6400, N=432)
    gemm_bias_kernel<<<dim3(N_ / 64, (G_ + 63) / 64), 256, 0, stream>>>(
        seq, w_ih, b_ih, gi, N_, G_);

    // K3: GRU over T=50
    gru_kernel<<<B_, 448, 0, stream>>>(gi, w_hh, b_hh, hidden, hseq,
                                       out + (size_t)N_ * E_);

    // K4: dynamic_user = hseq @ fc_w^T + fc_b   (M=6400, N=128)
    gemm_bias_kernel<<<dim3(N_ / 64, E_ / 64), 256, 0, stream>>>(
        hseq, fc_w, fc_b, out, N_, E_);
}